// Round 1
// baseline (958.739 us; speedup 1.0000x reference)
//
#include <hip/hip_runtime.h>

// ---------------------------------------------------------------------------
// Fully-fused 4-layer LSTM (B=8192, T=200, IN=4, H=16) + MLP (3200->64->28).
// Design: one 64-lane wave per batch sample.
//   - lane g owns gate row g (4H = 64 rows exactly); all weights in VGPRs
//   - h state broadcast through SGPRs via v_readlane (wave-uniform)
//   - activations branch-free: exp2-based, log2e prefolded into weights
//   - MLP accumulated in-loop; W1 slice (4KB/step) staged in LDS by the
//     block's 4 lockstep waves (parity double buffer, 1 barrier/step)
//   - no intermediate HBM traffic: only x (26 MB), weights, out (0.9 MB)
// ---------------------------------------------------------------------------

namespace {
constexpr int kB     = 8192;
constexpr int kT     = 200;
constexpr int kIN    = 4;
constexpr int kH     = 16;
constexpr int kOut   = 28;
constexpr int kWaves = 4;   // waves (samples) per block
constexpr float kNLog2e  = -1.4426950408889634f;   // -log2(e)
constexpr float kN2Log2e = -2.8853900817779268f;   // -2*log2(e)
}

__device__ __forceinline__ float rdlane(float v, int j) {
    return __int_as_float(__builtin_amdgcn_readlane(__float_as_int(v), j));
}

__device__ __forceinline__ float fast_rcp(float v) {
    return __builtin_amdgcn_rcpf(v);
}

__device__ __forceinline__ float fast_exp2(float v) {
#if __has_builtin(__builtin_amdgcn_exp2f)
    return __builtin_amdgcn_exp2f(v);
#else
    return exp2f(v);
#endif
}

// tanh(x) = 2/(1+e^{-2x}) - 1 = 2*rcp(1+2^{-2x*log2e}) - 1
__device__ __forceinline__ float tanh_fast(float v) {
    float e = fast_exp2(kN2Log2e * v);
    return fmaf(fast_rcp(1.0f + e), 2.0f, -1.0f);
}

__global__ __launch_bounds__(256, 2)
void lstm_mlp_fused(const float* __restrict__ x,     // [B,T,4]
                    const float* __restrict__ Wih0,  // [64,4]
                    const float* __restrict__ Wihr,  // [3,64,16]
                    const float* __restrict__ Whh,   // [4,64,16]
                    const float* __restrict__ bih,   // [4,64]
                    const float* __restrict__ bhh,   // [4,64]
                    const float* __restrict__ W1,    // [64,3200]
                    const float* __restrict__ b1,    // [64]
                    const float* __restrict__ W2,    // [28,64]
                    const float* __restrict__ b2,    // [28]
                    float* __restrict__ out)         // [B,28]
{
    __shared__ float ldsW1[2][kH][64];   // transposed slice: [parity][j][u]
    __shared__ float ldsR[kWaves][64];   // relu(hid) per wave for W2 stage

    const int tid  = threadIdx.x;
    const int lane = tid & 63;
    const int wv   = tid >> 6;
    const int b    = blockIdx.x * kWaves + wv;

    // lane 0-15: i (sigmoid), 16-31: f (sigmoid), 32-47: g (tanh), 48-63: o
    const int   typ = lane >> 4;
    const float kE  = (typ == 2) ? kN2Log2e : kNLog2e;  // prefold into weights
    const float sA  = (typ == 2) ? 2.0f : 1.0f;         // act = sA*r + sB
    const float sB  = (typ == 2) ? -1.0f : 0.0f;

    // ---- load weights into VGPRs (scaled by kE so act = sA*rcp(1+2^pre)+sB)
    float wih0[kIN];
#pragma unroll
    for (int d = 0; d < kIN; ++d) wih0[d] = Wih0[lane * kIN + d] * kE;

    float wihr[3][kH];
#pragma unroll
    for (int l = 0; l < 3; ++l)
#pragma unroll
        for (int j = 0; j < kH; ++j)
            wihr[l][j] = Wihr[(l * 64 + lane) * kH + j] * kE;

    float whh[4][kH];
#pragma unroll
    for (int l = 0; l < 4; ++l)
#pragma unroll
        for (int j = 0; j < kH; ++j)
            whh[l][j] = Whh[(l * 64 + lane) * kH + j] * kE;

    float bias[4];
#pragma unroll
    for (int l = 0; l < 4; ++l)
        bias[l] = (bih[l * 64 + lane] + bhh[l * 64 + lane]) * kE;

    const float b1u = b1[lane];

    // ---- state
    float cc[4];
    float hs[4][kH];   // wave-uniform h (readlane results; compiler -> SGPR)
#pragma unroll
    for (int l = 0; l < 4; ++l) {
        cc[l] = 0.0f;
#pragma unroll
        for (int j = 0; j < kH; ++j) hs[l][j] = 0.0f;
    }
    float hidA = 0.0f, hidB = 0.0f;   // split MLP accumulator (shorter chain)

    const float* xp  = x + (size_t)b * (kT * kIN);
    const int    su  = tid >> 2;         // W1 row this thread stages (0..63)
    const int    sj  = (tid & 3) * 4;    // col offset within the 16-wide slice
    const float* w1p = W1 + (size_t)su * (kT * kH) + sj;

#pragma unroll 2
    for (int t = 0; t < kT; ++t) {
        // issue next W1 slice + x loads early; latency hides under the layers
        const float4 w4 = *(const float4*)(w1p + (size_t)t * kH);
        const float4 xv = *(const float4*)(xp + t * kIN);

        // ---------------- layer 0 (input dim 4) ----------------
        {
            float p0 = bias[0], p1 = 0.0f, p2 = 0.0f, p3 = 0.0f;
            p0 = fmaf(wih0[0], xv.x, p0);
            p1 = fmaf(wih0[1], xv.y, p1);
            p2 = fmaf(wih0[2], xv.z, p2);
            p3 = fmaf(wih0[3], xv.w, p3);
#pragma unroll
            for (int j = 0; j < kH; j += 4) {
                p0 = fmaf(whh[0][j + 0], hs[0][j + 0], p0);
                p1 = fmaf(whh[0][j + 1], hs[0][j + 1], p1);
                p2 = fmaf(whh[0][j + 2], hs[0][j + 2], p2);
                p3 = fmaf(whh[0][j + 3], hs[0][j + 3], p3);
            }
            const float pre = (p0 + p1) + (p2 + p3);
            const float act = fmaf(fast_rcp(1.0f + fast_exp2(pre)), sA, sB);
            const float gf = __shfl_down(act, 16);
            const float gg = __shfl_down(act, 32);
            const float go = __shfl_down(act, 48);
            cc[0] = fmaf(gf, cc[0], act * gg);      // lanes 0-15 meaningful
            const float hh = go * tanh_fast(cc[0]);
#pragma unroll
            for (int j = 0; j < kH; ++j) hs[0][j] = rdlane(hh, j);
        }

        // ---------------- layers 1..3 (input dim 16) ----------------
#pragma unroll
        for (int l = 1; l < 4; ++l) {
            float p0 = bias[l], p1 = 0.0f, p2 = 0.0f, p3 = 0.0f;
#pragma unroll
            for (int j = 0; j < kH; j += 4) {
                p0 = fmaf(wihr[l - 1][j + 0], hs[l - 1][j + 0], p0);
                p1 = fmaf(wihr[l - 1][j + 1], hs[l - 1][j + 1], p1);
                p2 = fmaf(wihr[l - 1][j + 2], hs[l - 1][j + 2], p2);
                p3 = fmaf(wihr[l - 1][j + 3], hs[l - 1][j + 3], p3);
            }
#pragma unroll
            for (int j = 0; j < kH; j += 4) {
                p0 = fmaf(whh[l][j + 0], hs[l][j + 0], p0);
                p1 = fmaf(whh[l][j + 1], hs[l][j + 1], p1);
                p2 = fmaf(whh[l][j + 2], hs[l][j + 2], p2);
                p3 = fmaf(whh[l][j + 3], hs[l][j + 3], p3);
            }
            const float pre = (p0 + p1) + (p2 + p3);
            const float act = fmaf(fast_rcp(1.0f + fast_exp2(pre)), sA, sB);
            const float gf = __shfl_down(act, 16);
            const float gg = __shfl_down(act, 32);
            const float go = __shfl_down(act, 48);
            cc[l] = fmaf(gf, cc[l], act * gg);
            const float hh = go * tanh_fast(cc[l]);
#pragma unroll
            for (int j = 0; j < kH; ++j) hs[l][j] = rdlane(hh, j);
        }

        // ---------------- fused MLP partial: hid += W1[:,t*16+j]*h3[j] -----
        {
            const int buf = t & 1;
            // transposed write: lds[j][u]; readers (lane=u) then hit distinct
            // banks (u % 32, 2-way aliasing = free)
            ldsW1[buf][sj + 0][su] = w4.x;
            ldsW1[buf][sj + 1][su] = w4.y;
            ldsW1[buf][sj + 2][su] = w4.z;
            ldsW1[buf][sj + 3][su] = w4.w;
            __syncthreads();   // parity double-buffer => single barrier/step
#pragma unroll
            for (int j = 0; j < kH; j += 2) {
                hidA = fmaf(ldsW1[buf][j + 0][lane], hs[3][j + 0], hidA);
                hidB = fmaf(ldsW1[buf][j + 1][lane], hs[3][j + 1], hidB);
            }
        }
    }

    // ---------------- epilogue: relu + out = W2 @ hid + b2 ----------------
    const float r = fmaxf((hidA + hidB) + b1u, 0.0f);
    ldsR[wv][lane] = r;
    __syncthreads();
    if (lane < kOut) {
        float acc = b2[lane];
#pragma unroll
        for (int u = 0; u < 64; ++u)
            acc = fmaf(W2[lane * 64 + u], ldsR[wv][u], acc);
        out[(size_t)b * kOut + lane] = acc;
    }
}

extern "C" void kernel_launch(void* const* d_in, const int* in_sizes, int n_in,
                              void* d_out, int out_size, void* d_ws, size_t ws_size,
                              hipStream_t stream) {
    (void)in_sizes; (void)n_in; (void)d_ws; (void)ws_size; (void)out_size;
    const float* x    = (const float*)d_in[0];
    const float* Wih0 = (const float*)d_in[1];
    const float* Wihr = (const float*)d_in[2];
    const float* Whh  = (const float*)d_in[3];
    const float* bih  = (const float*)d_in[4];
    const float* bhh  = (const float*)d_in[5];
    const float* W1   = (const float*)d_in[6];
    const float* b1   = (const float*)d_in[7];
    const float* W2   = (const float*)d_in[8];
    const float* b2   = (const float*)d_in[9];
    float* out = (float*)d_out;

    dim3 grid(kB / kWaves), block(256);
    hipLaunchKernelGGL(lstm_mlp_fused, grid, block, 0, stream,
                       x, Wih0, Wihr, Whh, bih, bhh, W1, b1, W2, b2, out);
}

// Round 2
// 515.925 us; speedup vs baseline: 1.8583x; 1.8583x over previous
//
#include <hip/hip_runtime.h>

// ---------------------------------------------------------------------------
// MFMA-based fused 4-layer LSTM (B=8192,T=200,IN=4,H=16) + MLP (3200->64->28).
//   - one 64-lane wave = 16 batch samples, fully independent (no barriers)
//   - per layer: G[64,32s] = [Wih|Whh][64,32] @ [h_{l-1};h_l][32,16] via
//     mfma_f32_16x16x32_bf16, 4 row-tiles (tile == gate type i/f/g/o)
//   - fp32-grade precision: trunc hi/lo bf16 split, 3-term (hh + hl + lh)
//   - C/D layout (HW-verified m89): col=lane&15 (sample), row=4*(lane>>4)+reg
//     -> i,f,g,o for 4 j's land in the SAME lane: state update lane-local
//   - h cross-lane exchange via tiny per-wave LDS buffer (same-wave lgkmcnt)
//   - MLP: K=32 (two t-slices of W1, bf16-split on the fly) accumulated in
//     4 f32x4 frags over all 200 steps; bias C-init frags live in LDS
// ---------------------------------------------------------------------------

typedef short  bf16x8 __attribute__((ext_vector_type(8)));
typedef float  f32x4  __attribute__((ext_vector_type(4)));

namespace {
constexpr int kT   = 200;
constexpr int kOut = 28;
constexpr float kNLog2e  = -1.4426950408889634f;   // -log2(e)
constexpr float kN2Log2e = -2.8853900817779268f;   // -2*log2(e)
}

union FragU { bf16x8 v; unsigned u[4]; };

__device__ __forceinline__ float fast_rcp(float v){ return __builtin_amdgcn_rcpf(v); }
__device__ __forceinline__ float fast_exp2(float v){ return __builtin_amdgcn_exp2f(v); }
// input already scaled by -log2e (folded into weights+bias)
__device__ __forceinline__ float sig_scaled(float p){ return fast_rcp(1.0f + fast_exp2(p)); }
__device__ __forceinline__ float tanh_true(float v){
  return fmaf(fast_rcp(1.0f + fast_exp2(kN2Log2e*v)), 2.0f, -1.0f);
}

// trunc-split 8 f32 -> bf16 hi frag + bf16 lo frag (exact: f = hi + lo + O(2^-16 f))
__device__ __forceinline__ void split8(const float* v, FragU& hi, FragU& lo){
#pragma unroll
  for (int r=0;r<4;++r){
    unsigned ua=__float_as_uint(v[2*r]), ub=__float_as_uint(v[2*r+1]);
    hi.u[r] = (ua>>16) | (ub & 0xffff0000u);
    float af=__uint_as_float(ua & 0xffff0000u);
    float bf=__uint_as_float(ub & 0xffff0000u);
    float al=v[2*r]-af, bl=v[2*r+1]-bf;
    lo.u[r] = (__float_as_uint(al)>>16) | (__float_as_uint(bl) & 0xffff0000u);
  }
}

__global__ __launch_bounds__(64,1)
void lstm_mfma(const float* __restrict__ x,     // [B,T,4]
               const float* __restrict__ Wih0,  // [64,4]
               const float* __restrict__ Wihr,  // [3,64,16]
               const float* __restrict__ Whh,   // [4,64,16]
               const float* __restrict__ bih,   // [4,64]
               const float* __restrict__ bhh,   // [4,64]
               const float* __restrict__ W1,    // [64,3200]
               const float* __restrict__ b1,    // [64]
               const float* __restrict__ W2,    // [28,64]
               const float* __restrict__ b2,    // [28]
               float* __restrict__ out)         // [B,28]
{
  __shared__ float ldsH[4][16][16];  // per-layer h, [layer][sample][j]
  __shared__ float ldsB[4][64];      // scaled bias, [layer][row]
  __shared__ float ldsR[16][68];     // relu(hid) for epilogue, padded

  const int lane = threadIdx.x;
  const int s = lane & 15;          // sample within wave (= MFMA col)
  const int q = lane >> 4;          // lane quadrant (= k-chunk / row group)
  const int sbase = blockIdx.x * 16;

  // ---- scaled bias -> LDS (row = lane; gate type = lane>>4)
  {
    const float kEl = ((lane>>4)==2) ? kN2Log2e : kNLog2e;
#pragma unroll
    for (int l=0;l<4;++l)
      ldsB[l][lane] = (bih[l*64+lane] + bhh[l*64+lane]) * kEl;
  }
  // ---- zero h state
#pragma unroll
  for (int i=0;i<16;++i) ((float*)ldsH)[lane + 64*i] = 0.0f;

  // ---- A fragments: row (within tile) = lane&15, k = q*8+e. tile = gate type.
  FragU A[4][4][2];
#pragma unroll
  for (int l=0;l<4;++l){
#pragma unroll
    for (int tile=0;tile<4;++tile){
      const int grow = tile*16 + s;
      const float kE = (tile==2) ? kN2Log2e : kNLog2e;
      float v[8];
      if (l==0){
        // A = [Wih0 (k0-3) | 0 (k4-15) | Whh0 (k16-31)]
#pragma unroll
        for (int e=0;e<8;++e){
          float w = 0.0f;
          if (q==0 && e<4) w = Wih0[grow*4+e];
          if (q>=2)        w = Whh[(0*64+grow)*16 + (q&1)*8 + e];
          v[e] = w * kE;
        }
      } else {
        // A = [Wih_l (k0-15) | Whh_l (k16-31)]
#pragma unroll
        for (int e=0;e<8;++e){
          float w = (q<2) ? Wihr[((l-1)*64+grow)*16 + q*8 + e]
                          : Whh [((l  )*64+grow)*16 + (q&1)*8 + e];
          v[e] = w * kE;
        }
      }
      split8(v, A[l][tile][0], A[l][tile][1]);
    }
  }

  const float* xp = x + (size_t)(sbase + s) * (kT*4);
  const float* w1row[4];
#pragma unroll
  for (int tile=0;tile<4;++tile) w1row[tile] = W1 + (size_t)(tile*16+s)*3200;

  f32x4 mlpacc[4];
#pragma unroll
  for (int tile=0;tile<4;++tile) mlpacc[tile] = (f32x4){0.f,0.f,0.f,0.f};
  float cst[4][4];
#pragma unroll
  for (int l=0;l<4;++l)
#pragma unroll
    for (int r=0;r<4;++r) cst[l][r]=0.f;

  float bufE[8];                     // even-step h3 stash for K=32 MLP MFMA
#pragma unroll
  for (int e=0;e<8;++e) bufE[e]=0.f;

  for (int t=0;t<kT;++t){
    // ================= recurrent layers =================
#pragma unroll
    for (int l=0;l<4;++l){
      // B operand: k = q*8+e.  q0,q1 <- fresh h_{l-1} (or x for l=0),
      //                        q2,q3 <- stale h_l (read BEFORE this layer's write)
      float bv[8];
      {
        const int srcl = (l==0) ? 0 : ((q<2) ? l-1 : l);
        const float* hp = &ldsH[srcl][s][(q&1)*8];
        const float4 h0 = *(const float4*)hp;
        const float4 h1 = *(const float4*)(hp+4);
        bv[0]=h0.x; bv[1]=h0.y; bv[2]=h0.z; bv[3]=h0.w;
        bv[4]=h1.x; bv[5]=h1.y; bv[6]=h1.z; bv[7]=h1.w;
      }
      if (l==0){
        if (q==0){
          const float4 xv = *(const float4*)(xp + 4*t);
          bv[0]=xv.x; bv[1]=xv.y; bv[2]=xv.z; bv[3]=xv.w;
          bv[4]=0.f; bv[5]=0.f; bv[6]=0.f; bv[7]=0.f;
        } else if (q==1){
#pragma unroll
          for (int e=0;e<8;++e) bv[e]=0.f;
        }
      }
      FragU Bh, Bl;
      split8(bv, Bh, Bl);

      float si[4], sf[4], sg[4], so[4];
#pragma unroll
      for (int tile=0;tile<4;++tile){
        f32x4 acc = *(const f32x4*)&ldsB[l][tile*16 + 4*q];   // C init = bias
        acc = __builtin_amdgcn_mfma_f32_16x16x32_bf16(A[l][tile][0].v, Bh.v, acc, 0,0,0);
        acc = __builtin_amdgcn_mfma_f32_16x16x32_bf16(A[l][tile][0].v, Bl.v, acc, 0,0,0);
        acc = __builtin_amdgcn_mfma_f32_16x16x32_bf16(A[l][tile][1].v, Bh.v, acc, 0,0,0);
#pragma unroll
        for (int r=0;r<4;++r){
          const float a = sig_scaled(acc[r]);
          if      (tile==0) si[r]=a;
          else if (tile==1) sf[r]=a;
          else if (tile==2) sg[r]=fmaf(a,2.f,-1.f);
          else              so[r]=a;
        }
      }
      float hn[4];
#pragma unroll
      for (int r=0;r<4;++r){
        cst[l][r] = fmaf(sf[r], cst[l][r], si[r]*sg[r]);
        hn[r] = so[r] * tanh_true(cst[l][r]);
      }
      *(float4*)&ldsH[l][s][4*q] = make_float4(hn[0],hn[1],hn[2],hn[3]);
    }

    // ================= fused MLP (K=32 over step pairs) =================
    {
      const float* hp = &ldsH[3][s][(q&1)*8];
      const float4 h0 = *(const float4*)hp;
      const float4 h1 = *(const float4*)(hp+4);
      if ((t & 1) == 0){
        bufE[0]=h0.x; bufE[1]=h0.y; bufE[2]=h0.z; bufE[3]=h0.w;
        bufE[4]=h1.x; bufE[5]=h1.y; bufE[6]=h1.z; bufE[7]=h1.w;
      } else {
        float bv[8];
        if (q<2){
#pragma unroll
          for (int e=0;e<8;++e) bv[e]=bufE[e];     // k0-15: even-step h3
        } else {
          bv[0]=h0.x; bv[1]=h0.y; bv[2]=h0.z; bv[3]=h0.w;  // k16-31: odd-step h3
          bv[4]=h1.x; bv[5]=h1.y; bv[6]=h1.z; bv[7]=h1.w;
        }
        FragU Bh,Bl; split8(bv,Bh,Bl);
        const int off = 16*(t-1) + q*8;            // W1 cols 16(t-1) .. 16t+15
#pragma unroll
        for (int tile=0;tile<4;++tile){
          float v[8];
          const float4 wa = *(const float4*)(w1row[tile]+off);
          const float4 wb = *(const float4*)(w1row[tile]+off+4);
          v[0]=wa.x; v[1]=wa.y; v[2]=wa.z; v[3]=wa.w;
          v[4]=wb.x; v[5]=wb.y; v[6]=wb.z; v[7]=wb.w;
          FragU Ah,Al; split8(v,Ah,Al);
          mlpacc[tile] = __builtin_amdgcn_mfma_f32_16x16x32_bf16(Ah.v,Bh.v,mlpacc[tile],0,0,0);
          mlpacc[tile] = __builtin_amdgcn_mfma_f32_16x16x32_bf16(Ah.v,Bl.v,mlpacc[tile],0,0,0);
          mlpacc[tile] = __builtin_amdgcn_mfma_f32_16x16x32_bf16(Al.v,Bh.v,mlpacc[tile],0,0,0);
        }
      }
    }
  }

  // ================= epilogue: relu + W2 =================
#pragma unroll
  for (int tile=0;tile<4;++tile){
    const float4 b1v = *(const float4*)(b1 + tile*16 + 4*q);
    float4 rv;
    rv.x = fmaxf(mlpacc[tile][0] + b1v.x, 0.f);
    rv.y = fmaxf(mlpacc[tile][1] + b1v.y, 0.f);
    rv.z = fmaxf(mlpacc[tile][2] + b1v.z, 0.f);
    rv.w = fmaxf(mlpacc[tile][3] + b1v.w, 0.f);
    *(float4*)&ldsR[s][tile*16 + 4*q] = rv;
  }
  const int o  = lane & 31;
  const int oc = (o < kOut) ? o : 0;
  float4 w2r[16];
#pragma unroll
  for (int c2=0;c2<16;++c2) w2r[c2] = *(const float4*)(W2 + oc*64 + 4*c2);
  const float bias2 = b2[oc];
#pragma unroll
  for (int m=0;m<8;++m){
    const int s2 = 2*m + (lane>>5);
    float a0=bias2, a1=0.f, a2=0.f, a3=0.f;
#pragma unroll
    for (int c2=0;c2<16;++c2){
      const float4 rv = *(const float4*)&ldsR[s2][4*c2];
      a0 = fmaf(w2r[c2].x, rv.x, a0);
      a1 = fmaf(w2r[c2].y, rv.y, a1);
      a2 = fmaf(w2r[c2].z, rv.z, a2);
      a3 = fmaf(w2r[c2].w, rv.w, a3);
    }
    if (o < kOut) out[(size_t)(sbase+s2)*kOut + o] = (a0+a1)+(a2+a3);
  }
}

extern "C" void kernel_launch(void* const* d_in, const int* in_sizes, int n_in,
                              void* d_out, int out_size, void* d_ws, size_t ws_size,
                              hipStream_t stream) {
  (void)in_sizes; (void)n_in; (void)d_ws; (void)ws_size; (void)out_size;
  const float* x    = (const float*)d_in[0];
  const float* Wih0 = (const float*)d_in[1];
  const float* Wihr = (const float*)d_in[2];
  const float* Whh  = (const float*)d_in[3];
  const float* bih  = (const float*)d_in[4];
  const float* bhh  = (const float*)d_in[5];
  const float* W1   = (const float*)d_in[6];
  const float* b1   = (const float*)d_in[7];
  const float* W2   = (const float*)d_in[8];
  const float* b2   = (const float*)d_in[9];
  float* out = (float*)d_out;

  dim3 grid(8192/16), block(64);
  hipLaunchKernelGGL(lstm_mfma, grid, block, 0, stream,
                     x, Wih0, Wihr, Whh, bih, bhh, W1, b1, W2, b2, out);
}

// Round 4
// 330.346 us; speedup vs baseline: 2.9022x; 1.5618x over previous
//
#include <hip/hip_runtime.h>
#include <hip/hip_bf16.h>

// ---------------------------------------------------------------------------
// Pipelined MFMA LSTM (B=8192,T=200,IN=4,H=16) + fused MLP (3200->64->28).
//   - block = 4 waves = one 16-sample group; wave l owns layer l AND MLP tile l
//   - software pipeline: superstep n, wave l computes t = n - l; h flows
//     through parity double-buffered LDS [2][4][16][16]; ONE barrier/superstep
//   - per layer: G[64,32] = [Wih|Whh] @ [h_{l-1};h_l] via mfma_f32_16x16x32_bf16
//     (3-term trunc hi/lo bf16 split for fp32-grade accuracy)
//   - MLP tile l: K=32 over step pairs, consumes h3[n-4]; W1 pre-split into
//     bf16 hi/lo planes in d_ws (bit-identical to runtime trunc split)
//   - W1 + x prefetched one superstep ahead (latency hidden under compute)
// ---------------------------------------------------------------------------

typedef short  bf16x8 __attribute__((ext_vector_type(8)));
typedef float  f32x4  __attribute__((ext_vector_type(4)));

namespace {
constexpr int kT     = 200;
constexpr int kOut   = 28;
constexpr int kSteps = kT + 4;            // 4-stage pipeline fill
constexpr float kNLog2e  = -1.4426950408889634f;   // -log2(e)
constexpr float kN2Log2e = -2.8853900817779268f;   // -2*log2(e)
constexpr int kW1Elems = 64 * 3200;
}

union FragU { bf16x8 v; unsigned u[4]; };

__device__ __forceinline__ float fast_rcp(float v){ return __builtin_amdgcn_rcpf(v); }
__device__ __forceinline__ float fast_exp2(float v){ return __builtin_amdgcn_exp2f(v); }
// input already scaled by -log2e (folded into weights+bias)
__device__ __forceinline__ float sig_scaled(float p){ return fast_rcp(1.0f + fast_exp2(p)); }
__device__ __forceinline__ float tanh_true(float v){
  return fmaf(fast_rcp(1.0f + fast_exp2(kN2Log2e*v)), 2.0f, -1.0f);
}

// trunc-split 8 f32 -> bf16 hi frag + bf16 lo frag
__device__ __forceinline__ void split8(const float* v, FragU& hi, FragU& lo){
#pragma unroll
  for (int r=0;r<4;++r){
    unsigned ua=__float_as_uint(v[2*r]), ub=__float_as_uint(v[2*r+1]);
    hi.u[r] = (ua>>16) | (ub & 0xffff0000u);
    float af=__uint_as_float(ua & 0xffff0000u);
    float bf=__uint_as_float(ub & 0xffff0000u);
    float al=v[2*r]-af, bl=v[2*r+1]-bf;
    lo.u[r] = (__float_as_uint(al)>>16) | (__float_as_uint(bl) & 0xffff0000u);
  }
}

__global__ __launch_bounds__(256)
void presplit_w1(const float* __restrict__ W1,
                 short* __restrict__ W1h, short* __restrict__ W1l){
  int i = blockIdx.x*256 + threadIdx.x;
  if (i < kW1Elems){
    float v = W1[i];
    unsigned u = __float_as_uint(v);
    float hif = __uint_as_float(u & 0xffff0000u);
    float lo  = v - hif;
    W1h[i] = (short)(u >> 16);
    W1l[i] = (short)(__float_as_uint(lo) >> 16);
  }
}

template<bool PS>
__global__ __launch_bounds__(256)
void lstm_pipe(const float* __restrict__ x,     // [B,T,4]
               const float* __restrict__ Wih0,  // [64,4]
               const float* __restrict__ Wihr,  // [3,64,16]
               const float* __restrict__ Whh,   // [4,64,16]
               const float* __restrict__ bih,   // [4,64]
               const float* __restrict__ bhh,   // [4,64]
               const float* __restrict__ W1,    // [64,3200]
               const float* __restrict__ b1,    // [64]
               const float* __restrict__ W2,    // [28,64]
               const float* __restrict__ b2,    // [28]
               const short* __restrict__ W1h,   // [64,3200] bf16 hi plane
               const short* __restrict__ W1l,   // [64,3200] bf16 lo plane
               float* __restrict__ out)         // [B,28]
{
  __shared__ float ldsH[2][4][16][16];  // [parity][layer][sample][j]
  __shared__ float ldsR[16][68];        // relu(hid), padded

  const int tid  = threadIdx.x;
  const int lane = tid & 63;
  const int wv   = tid >> 6;            // 0..3: layer index AND mlp tile index
  const int s    = lane & 15;           // sample within group (= MFMA col)
  const int q    = lane >> 4;           // lane quadrant (= k-chunk / row group)
  const int l    = wv;
  const int sbase = blockIdx.x * 16;

  for (int i = tid; i < 2*4*16*16; i += 256) ((float*)ldsH)[i] = 0.f;

  // ---- A fragments for THIS wave's layer: row=lane&15, k=q*8+e, tile=gate
  FragU A[4][2];
#pragma unroll
  for (int tile=0;tile<4;++tile){
    const int grow = tile*16 + s;
    const float kE = (tile==2)? kN2Log2e : kNLog2e;
    float v[8];
    if (l==0){
#pragma unroll
      for (int e=0;e<8;++e){
        float w = 0.f;
        if (q==0 && e<4) w = Wih0[grow*4+e];
        if (q>=2)        w = Whh[grow*16 + (q&1)*8 + e];
        v[e] = w*kE;
      }
    } else {
#pragma unroll
      for (int e=0;e<8;++e){
        float w = (q<2) ? Wihr[((l-1)*64+grow)*16 + q*8 + e]
                        : Whh [(( l )*64+grow)*16 + (q&1)*8 + e];
        v[e] = w*kE;
      }
    }
    split8(v, A[tile][0], A[tile][1]);
  }

  // ---- scaled bias in VGPRs (C-init)
  f32x4 biasf[4];
#pragma unroll
  for (int tile=0;tile<4;++tile){
    const float kE = (tile==2)? kN2Log2e : kNLog2e;
#pragma unroll
    for (int r=0;r<4;++r){
      const int row = l*64 + tile*16 + 4*q + r;
      biasf[tile][r] = (bih[row] + bhh[row]) * kE;
    }
  }

  float cst[4] = {0.f,0.f,0.f,0.f};
  f32x4 mlpacc = (f32x4){0.f,0.f,0.f,0.f};
  float bufE[8];
#pragma unroll
  for (int e=0;e<8;++e) bufE[e]=0.f;

  const float* xp = x + (size_t)(sbase+s)*(kT*4);
  float4 xv_cur;
  if (l==0) xv_cur = *(const float4*)xp;

  const int rowW1 = wv*16 + s;
  const short* w1hp = W1h + (size_t)rowW1*3200;
  const short* w1lp = W1l + (size_t)rowW1*3200;
  const float* w1fp = W1  + (size_t)rowW1*3200;
  FragU  pWh, pWl;     // presplit prefetch regs
  float4 pWa, pWb;     // f32 fallback prefetch regs

  __syncthreads();

  for (int n=0; n<kSteps; ++n){
    const int p = n & 1;
    const float (*rb)[16][16] = ldsH[p^1];   // written at superstep n-1
    float (*wb)[16][16] = ldsH[p];

    // ---- 1) W1 prefetch (consumed next superstep, odd tm)
    const int tm = n - 4;
    if (tm >= 0 && tm < kT && (tm&1)==0){
      const int off = 16*tm + q*8;
      if (PS){
        pWh.v = *(const bf16x8*)(w1hp + off);
        pWl.v = *(const bf16x8*)(w1lp + off);
      } else {
        pWa = *(const float4*)(w1fp + off);
        pWb = *(const float4*)(w1fp + off + 4);
      }
    }
    // ---- 1b) x prefetch (wave 0)
    const int t = n - l;
    float4 xv_next;
    if (l==0 && t+1 < kT) xv_next = *(const float4*)(xp + 4*(t+1));

    // ---- 2) recurrent layer l at time t
    if (t >= 0 && t < kT){
      // B operand: k=q*8+e. q0,q1 <- h_{l-1}[t] (x for l=0); q2,q3 <- h_l[t-1]
      float bv[8];
      {
        const int srcl = (q<2) ? ((l==0)?0:(l-1)) : l;
        const float* hp = &rb[srcl][s][(q&1)*8];
        const float4 h0 = *(const float4*)hp;
        const float4 h1 = *(const float4*)(hp+4);
        bv[0]=h0.x; bv[1]=h0.y; bv[2]=h0.z; bv[3]=h0.w;
        bv[4]=h1.x; bv[5]=h1.y; bv[6]=h1.z; bv[7]=h1.w;
      }
      if (l==0){
        if (q==0){
          bv[0]=xv_cur.x; bv[1]=xv_cur.y; bv[2]=xv_cur.z; bv[3]=xv_cur.w;
          bv[4]=0.f; bv[5]=0.f; bv[6]=0.f; bv[7]=0.f;
        } else if (q==1){
#pragma unroll
          for (int e=0;e<8;++e) bv[e]=0.f;
        }
      }
      FragU Bh,Bl; split8(bv,Bh,Bl);

      float si[4], sf[4], sg[4], so[4];
#pragma unroll
      for (int tile=0;tile<4;++tile){
        f32x4 acc = biasf[tile];
        acc = __builtin_amdgcn_mfma_f32_16x16x32_bf16(A[tile][0].v,Bh.v,acc,0,0,0);
        acc = __builtin_amdgcn_mfma_f32_16x16x32_bf16(A[tile][0].v,Bl.v,acc,0,0,0);
        acc = __builtin_amdgcn_mfma_f32_16x16x32_bf16(A[tile][1].v,Bh.v,acc,0,0,0);
#pragma unroll
        for (int r=0;r<4;++r){
          const float a = sig_scaled(acc[r]);
          if      (tile==0) si[r]=a;
          else if (tile==1) sf[r]=a;
          else if (tile==2) sg[r]=fmaf(a,2.f,-1.f);
          else              so[r]=a;
        }
      }
      float hn[4];
#pragma unroll
      for (int r=0;r<4;++r){
        cst[r] = fmaf(sf[r], cst[r], si[r]*sg[r]);
        hn[r] = so[r]*tanh_true(cst[r]);
      }
      f32x4 hv = (f32x4){hn[0],hn[1],hn[2],hn[3]};
      *(f32x4*)&wb[l][s][4*q] = hv;
    }
    if (l==0 && t+1 < kT) xv_cur = xv_next;

    // ---- 3) MLP tile wv at time tm (K=32 over step pairs)
    if (tm >= 0 && tm < kT){
      const float* hp3 = &rb[3][s][(q&1)*8];
      const float4 h0 = *(const float4*)hp3;
      const float4 h1 = *(const float4*)(hp3+4);
      if ((tm & 1) == 0){
        bufE[0]=h0.x; bufE[1]=h0.y; bufE[2]=h0.z; bufE[3]=h0.w;
        bufE[4]=h1.x; bufE[5]=h1.y; bufE[6]=h1.z; bufE[7]=h1.w;
      } else {
        float bv[8];
        if (q<2){
#pragma unroll
          for (int e=0;e<8;++e) bv[e]=bufE[e];     // k0-15: even-step h3
        } else {
          bv[0]=h0.x; bv[1]=h0.y; bv[2]=h0.z; bv[3]=h0.w;  // k16-31: odd-step
          bv[4]=h1.x; bv[5]=h1.y; bv[6]=h1.z; bv[7]=h1.w;
        }
        FragU Bh,Bl; split8(bv,Bh,Bl);
        FragU Ah,Al;
        if (PS){ Ah = pWh; Al = pWl; }
        else {
          float v[8] = {pWa.x,pWa.y,pWa.z,pWa.w,pWb.x,pWb.y,pWb.z,pWb.w};
          split8(v,Ah,Al);
        }
        mlpacc = __builtin_amdgcn_mfma_f32_16x16x32_bf16(Ah.v,Bh.v,mlpacc,0,0,0);
        mlpacc = __builtin_amdgcn_mfma_f32_16x16x32_bf16(Ah.v,Bl.v,mlpacc,0,0,0);
        mlpacc = __builtin_amdgcn_mfma_f32_16x16x32_bf16(Al.v,Bh.v,mlpacc,0,0,0);
      }
    }
    __syncthreads();
  }

  // ---- epilogue: relu -> ldsR; W2 stage spread over the 4 waves
  {
    f32x4 rv;
#pragma unroll
    for (int r=0;r<4;++r)
      rv[r] = fmaxf(mlpacc[r] + b1[wv*16 + 4*q + r], 0.f);
    *(f32x4*)&ldsR[s][wv*16 + 4*q] = rv;
  }
  __syncthreads();
  {
    const int o  = lane & 31;
    const int oc = (o < kOut) ? o : 0;
    float4 w2r[16];
#pragma unroll
    for (int c2=0;c2<16;++c2) w2r[c2] = *(const float4*)(W2 + oc*64 + 4*c2);
    const float bias2 = b2[oc];
#pragma unroll
    for (int mm=0;mm<2;++mm){
      const int s2 = wv*4 + 2*mm + (lane>>5);
      float a0=bias2, a1=0.f, a2=0.f, a3=0.f;
#pragma unroll
      for (int c2=0;c2<16;++c2){
        const float4 rvv = *(const float4*)&ldsR[s2][4*c2];
        a0 = fmaf(w2r[c2].x, rvv.x, a0);
        a1 = fmaf(w2r[c2].y, rvv.y, a1);
        a2 = fmaf(w2r[c2].z, rvv.z, a2);
        a3 = fmaf(w2r[c2].w, rvv.w, a3);
      }
      if (o < kOut) out[(size_t)(sbase+s2)*kOut + o] = (a0+a1)+(a2+a3);
    }
  }
}

extern "C" void kernel_launch(void* const* d_in, const int* in_sizes, int n_in,
                              void* d_out, int out_size, void* d_ws, size_t ws_size,
                              hipStream_t stream) {
  (void)in_sizes; (void)n_in; (void)out_size;
  const float* x    = (const float*)d_in[0];
  const float* Wih0 = (const float*)d_in[1];
  const float* Wihr = (const float*)d_in[2];
  const float* Whh  = (const float*)d_in[3];
  const float* bih  = (const float*)d_in[4];
  const float* bhh  = (const float*)d_in[5];
  const float* W1   = (const float*)d_in[6];
  const float* b1   = (const float*)d_in[7];
  const float* W2   = (const float*)d_in[8];
  const float* b2   = (const float*)d_in[9];
  float* out = (float*)d_out;

  const size_t splitBytes = (size_t)kW1Elems * sizeof(short) * 2;
  dim3 grid(8192/16), block(256);
  if (ws_size >= splitBytes) {
    short* W1h = (short*)d_ws;
    short* W1l = W1h + kW1Elems;
    hipLaunchKernelGGL(presplit_w1, dim3((kW1Elems+255)/256), dim3(256), 0, stream,
                       W1, W1h, W1l);
    hipLaunchKernelGGL(lstm_pipe<true>, grid, block, 0, stream,
                       x, Wih0, Wihr, Whh, bih, bhh, W1, b1, W2, b2, W1h, W1l, out);
  } else {
    hipLaunchKernelGGL(lstm_pipe<false>, grid, block, 0, stream,
                       x, Wih0, Wihr, Whh, bih, bhh, W1, b1, W2, b2,
                       (const short*)nullptr, (const short*)nullptr, out);
  }
}

// Round 6
// 293.363 us; speedup vs baseline: 3.2681x; 1.1261x over previous
//
#include <hip/hip_runtime.h>
#include <hip/hip_bf16.h>

// ---------------------------------------------------------------------------
// Pipelined MFMA LSTM (B=8192,T=200,IN=4,H=16) + fused MLP (3200->64->28).
//   - block = 4 waves = one 16-sample group; wave l owns layer l AND MLP tile l
//   - software pipeline over timestep PAIRS: superstep n, wave l computes
//     t = 2(n-l) and 2(n-l)+1; h flows through parity double-buffered LDS
//     [2][4][2][16][20] (row pad 16->20 kills the 8-way bank conflict);
//     ONE barrier per 2 timesteps
//   - step B reads its own step-A h from the just-written LDS slot
//     (same-wave lgkmcnt ordering, validated pattern)
//   - per layer: G[64,32] = [Wih|Whh] @ [h_{l-1};h_l] via mfma_f32_16x16x32_bf16
//     (3-term trunc hi/lo bf16 split for fp32-grade accuracy)
//   - MLP tile l: one K=32 MFMA triple per superstep over the (even,odd) h3
//     pair; W1 pre-split into bf16 hi/lo planes in d_ws; prefetched 1 ahead
//     into SEPARATE regs (R5 bug: same-reg prefetch clobbered the consumer)
// ---------------------------------------------------------------------------

typedef short  bf16x8 __attribute__((ext_vector_type(8)));
typedef float  f32x4  __attribute__((ext_vector_type(4)));

namespace {
constexpr int kT     = 200;
constexpr int kOut   = 28;
constexpr int kPairs = kT / 2;            // 100
constexpr int kSteps = kPairs + 4;        // 4-stage pipeline fill
constexpr float kNLog2e  = -1.4426950408889634f;   // -log2(e)
constexpr float kN2Log2e = -2.8853900817779268f;   // -2*log2(e)
constexpr int kW1Elems = 64 * 3200;
}

union FragU { bf16x8 v; unsigned u[4]; };

__device__ __forceinline__ float fast_rcp(float v){ return __builtin_amdgcn_rcpf(v); }
__device__ __forceinline__ float fast_exp2(float v){ return __builtin_amdgcn_exp2f(v); }
// input already scaled by -log2e (folded into weights+bias)
__device__ __forceinline__ float sig_scaled(float p){ return fast_rcp(1.0f + fast_exp2(p)); }
__device__ __forceinline__ float tanh_true(float v){
  return fmaf(fast_rcp(1.0f + fast_exp2(kN2Log2e*v)), 2.0f, -1.0f);
}

// trunc-split 8 f32 -> bf16 hi frag + bf16 lo frag
__device__ __forceinline__ void split8(const float* v, FragU& hi, FragU& lo){
#pragma unroll
  for (int r=0;r<4;++r){
    unsigned ua=__float_as_uint(v[2*r]), ub=__float_as_uint(v[2*r+1]);
    hi.u[r] = (ua>>16) | (ub & 0xffff0000u);
    float af=__uint_as_float(ua & 0xffff0000u);
    float bf=__uint_as_float(ub & 0xffff0000u);
    float al=v[2*r]-af, bl=v[2*r+1]-bf;
    lo.u[r] = (__float_as_uint(al)>>16) | (__float_as_uint(bl) & 0xffff0000u);
  }
}

__global__ __launch_bounds__(256)
void presplit_w1(const float* __restrict__ W1,
                 short* __restrict__ W1h, short* __restrict__ W1l){
  int i = blockIdx.x*256 + threadIdx.x;
  if (i < kW1Elems){
    float v = W1[i];
    unsigned u = __float_as_uint(v);
    float hif = __uint_as_float(u & 0xffff0000u);
    float lo  = v - hif;
    W1h[i] = (short)(u >> 16);
    W1l[i] = (short)(__float_as_uint(lo) >> 16);
  }
}

template<bool PS>
__global__ __launch_bounds__(256)
void lstm_pipe(const float* __restrict__ x,     // [B,T,4]
               const float* __restrict__ Wih0,  // [64,4]
               const float* __restrict__ Wihr,  // [3,64,16]
               const float* __restrict__ Whh,   // [4,64,16]
               const float* __restrict__ bih,   // [4,64]
               const float* __restrict__ bhh,   // [4,64]
               const float* __restrict__ W1,    // [64,3200]
               const float* __restrict__ b1,    // [64]
               const float* __restrict__ W2,    // [28,64]
               const float* __restrict__ b2,    // [28]
               const short* __restrict__ W1h,   // [64,3200] bf16 hi plane
               const short* __restrict__ W1l,   // [64,3200] bf16 lo plane
               float* __restrict__ out)         // [B,28]
{
  // [parity][layer][step01][sample][j padded 16->20]
  __shared__ float ldsH[2][4][2][16][20];
  __shared__ float ldsR[16][68];        // relu(hid), padded

  const int tid  = threadIdx.x;
  const int lane = tid & 63;
  const int wv   = tid >> 6;            // 0..3: layer index AND mlp tile index
  const int s    = lane & 15;           // sample within group (= MFMA col)
  const int q    = lane >> 4;           // lane quadrant (= k-chunk / row group)
  const int l    = wv;
  const int lm1  = (l==0) ? 0 : (l-1);
  const int sbase = blockIdx.x * 16;

  for (int i = tid; i < 2*4*2*16*20; i += 256) ((float*)ldsH)[i] = 0.f;

  // ---- A fragments for THIS wave's layer: row=lane&15, k=q*8+e, tile=gate
  FragU A[4][2];
#pragma unroll
  for (int tile=0;tile<4;++tile){
    const int grow = tile*16 + s;
    const float kE = (tile==2)? kN2Log2e : kNLog2e;
    float v[8];
    if (l==0){
#pragma unroll
      for (int e=0;e<8;++e){
        float w = 0.f;
        if (q==0 && e<4) w = Wih0[grow*4+e];
        if (q>=2)        w = Whh[grow*16 + (q&1)*8 + e];
        v[e] = w*kE;
      }
    } else {
#pragma unroll
      for (int e=0;e<8;++e){
        float w = (q<2) ? Wihr[((l-1)*64+grow)*16 + q*8 + e]
                        : Whh [(( l )*64+grow)*16 + (q&1)*8 + e];
        v[e] = w*kE;
      }
    }
    split8(v, A[tile][0], A[tile][1]);
  }

  // ---- scaled bias in VGPRs (C-init)
  f32x4 biasf[4];
#pragma unroll
  for (int tile=0;tile<4;++tile){
    const float kE = (tile==2)? kN2Log2e : kNLog2e;
#pragma unroll
    for (int r=0;r<4;++r){
      const int row = l*64 + tile*16 + 4*q + r;
      biasf[tile][r] = (bih[row] + bhh[row]) * kE;
    }
  }

  float cst[4] = {0.f,0.f,0.f,0.f};
  f32x4 mlpacc = (f32x4){0.f,0.f,0.f,0.f};

  const float* xp = x + (size_t)(sbase+s)*(kT*4);
  float4 xA, xB;                 // x for current pair (wave 0 only)
  if (l==0){
    xA = *(const float4*)xp;
    xB = *(const float4*)(xp+4);
  }

  const int rowW1 = wv*16 + s;
  const short* w1hp = W1h + (size_t)rowW1*3200;
  const short* w1lp = W1l + (size_t)rowW1*3200;
  const float* w1fp = W1  + (size_t)rowW1*3200;
  // prefetch double-buffer: N = loaded this superstep, C = consumed this one
  FragU  pWhN, pWlN, pWhC, pWlC;
  float4 pWaN, pWbN, pWaC, pWbC;

  __syncthreads();

  for (int n=0; n<kSteps; ++n){
    const int p = n & 1;
    float (*rb)[2][16][20] = ldsH[p^1];   // written at superstep n-1
    float (*wb)[2][16][20] = ldsH[p];

    // ---- 1) W1 prefetch for MLP pair (n-3) into N regs (consumed at n+1)
    {
      const int mp = n - 3;
      if (mp >= 0 && mp < kPairs){
        const int off = 32*mp + q*8;
        if (PS){
          pWhN.v = *(const bf16x8*)(w1hp + off);
          pWlN.v = *(const bf16x8*)(w1lp + off);
        } else {
          pWaN = *(const float4*)(w1fp + off);
          pWbN = *(const float4*)(w1fp + off + 4);
        }
      }
    }
    const int pr = n - l;                 // this wave's timestep pair
    // ---- 1b) x prefetch for next pair (wave 0)
    float4 xnA, xnB;
    if (l==0 && pr+1 < kPairs){
      xnA = *(const float4*)(xp + 8*(pr+1));
      xnB = *(const float4*)(xp + 8*(pr+1) + 4);
    }

    // ---- 2) recurrent layer l, two timesteps of pair pr
    if (pr >= 0 && pr < kPairs){
#pragma unroll
      for (int st=0; st<2; ++st){
        // B operand: k=q*8+e.
        //  step A (st=0): q0,q1 <- h_{l-1}(2pr)   [rb lm1][0]; q2,q3 <- h_l(2pr-1) [rb l][1]
        //  step B (st=1): q0,q1 <- h_{l-1}(2pr+1) [rb lm1][1]; q2,q3 <- h_l(2pr)   [wb l][0]
        float bv[8];
        {
          const float* hp = (q < 2)
            ? &rb[lm1][st][s][(q&1)*8]
            : (st==0 ? &rb[l][1][s][(q&1)*8] : &wb[l][0][s][(q&1)*8]);
          const float4 h0 = *(const float4*)hp;
          const float4 h1 = *(const float4*)(hp+4);
          bv[0]=h0.x; bv[1]=h0.y; bv[2]=h0.z; bv[3]=h0.w;
          bv[4]=h1.x; bv[5]=h1.y; bv[6]=h1.z; bv[7]=h1.w;
        }
        if (l==0){
          if (q==0){
            const float4 xv = st==0 ? xA : xB;
            bv[0]=xv.x; bv[1]=xv.y; bv[2]=xv.z; bv[3]=xv.w;
            bv[4]=0.f; bv[5]=0.f; bv[6]=0.f; bv[7]=0.f;
          } else if (q==1){
#pragma unroll
            for (int e=0;e<8;++e) bv[e]=0.f;
          }
        }
        FragU Bh,Bl; split8(bv,Bh,Bl);

        float si[4], sf[4], sg[4], so[4];
#pragma unroll
        for (int tile=0;tile<4;++tile){
          f32x4 acc = biasf[tile];
          acc = __builtin_amdgcn_mfma_f32_16x16x32_bf16(A[tile][0].v,Bh.v,acc,0,0,0);
          acc = __builtin_amdgcn_mfma_f32_16x16x32_bf16(A[tile][0].v,Bl.v,acc,0,0,0);
          acc = __builtin_amdgcn_mfma_f32_16x16x32_bf16(A[tile][1].v,Bh.v,acc,0,0,0);
#pragma unroll
          for (int r=0;r<4;++r){
            const float a = sig_scaled(acc[r]);
            if      (tile==0) si[r]=a;
            else if (tile==1) sf[r]=a;
            else if (tile==2) sg[r]=fmaf(a,2.f,-1.f);
            else              so[r]=a;
          }
        }
        float hn[4];
#pragma unroll
        for (int r=0;r<4;++r){
          cst[r] = fmaf(sf[r], cst[r], si[r]*sg[r]);
          hn[r] = so[r]*tanh_true(cst[r]);
        }
        f32x4 hv = (f32x4){hn[0],hn[1],hn[2],hn[3]};
        *(f32x4*)&wb[l][st][s][4*q] = hv;   // step B reads st=0 slot same-wave
      }
    }
    if (l==0 && pr+1 < kPairs){ xA = xnA; xB = xnB; }

    // ---- 3) MLP tile wv for pair m = n-4 (K=32: even-step + odd-step h3),
    //         consuming the C regs loaded at superstep n-1
    {
      const int m = n - 4;
      if (m >= 0 && m < kPairs){
        float bv[8];
        {
          const float* hp3 = &rb[3][q>>1][s][(q&1)*8];
          const float4 h0 = *(const float4*)hp3;
          const float4 h1 = *(const float4*)(hp3+4);
          bv[0]=h0.x; bv[1]=h0.y; bv[2]=h0.z; bv[3]=h0.w;
          bv[4]=h1.x; bv[5]=h1.y; bv[6]=h1.z; bv[7]=h1.w;
        }
        FragU Bh,Bl; split8(bv,Bh,Bl);
        FragU Ah,Al;
        if (PS){ Ah = pWhC; Al = pWlC; }
        else {
          float v[8] = {pWaC.x,pWaC.y,pWaC.z,pWaC.w,pWbC.x,pWbC.y,pWbC.z,pWbC.w};
          split8(v,Ah,Al);
        }
        mlpacc = __builtin_amdgcn_mfma_f32_16x16x32_bf16(Ah.v,Bh.v,mlpacc,0,0,0);
        mlpacc = __builtin_amdgcn_mfma_f32_16x16x32_bf16(Ah.v,Bl.v,mlpacc,0,0,0);
        mlpacc = __builtin_amdgcn_mfma_f32_16x16x32_bf16(Al.v,Bh.v,mlpacc,0,0,0);
      }
    }
    // rotate prefetch regs AFTER consume (compiler renames on unroll)
    if (PS){ pWhC = pWhN; pWlC = pWlN; }
    else   { pWaC = pWaN; pWbC = pWbN; }
    __syncthreads();
  }

  // ---- epilogue: relu -> ldsR; W2 stage spread over the 4 waves
  {
    f32x4 rv;
#pragma unroll
    for (int r=0;r<4;++r)
      rv[r] = fmaxf(mlpacc[r] + b1[wv*16 + 4*q + r], 0.f);
    *(f32x4*)&ldsR[s][wv*16 + 4*q] = rv;
  }
  __syncthreads();
  {
    const int o  = lane & 31;
    const int oc = (o < kOut) ? o : 0;
    float4 w2r[16];
#pragma unroll
    for (int c2=0;c2<16;++c2) w2r[c2] = *(const float4*)(W2 + oc*64 + 4*c2);
    const float bias2 = b2[oc];
#pragma unroll
    for (int mm=0;mm<2;++mm){
      const int s2 = wv*4 + 2*mm + (lane>>5);
      float a0=bias2, a1=0.f, a2=0.f, a3=0.f;
#pragma unroll
      for (int c2=0;c2<16;++c2){
        const float4 rvv = *(const float4*)&ldsR[s2][4*c2];
        a0 = fmaf(w2r[c2].x, rvv.x, a0);
        a1 = fmaf(w2r[c2].y, rvv.y, a1);
        a2 = fmaf(w2r[c2].z, rvv.z, a2);
        a3 = fmaf(w2r[c2].w, rvv.w, a3);
      }
      if (o < kOut) out[(size_t)(sbase+s2)*kOut + o] = (a0+a1)+(a2+a3);
    }
  }
}

extern "C" void kernel_launch(void* const* d_in, const int* in_sizes, int n_in,
                              void* d_out, int out_size, void* d_ws, size_t ws_size,
                              hipStream_t stream) {
  (void)in_sizes; (void)n_in; (void)out_size;
  const float* x    = (const float*)d_in[0];
  const float* Wih0 = (const float*)d_in[1];
  const float* Wihr = (const float*)d_in[2];
  const float* Whh  = (const float*)d_in[3];
  const float* bih  = (const float*)d_in[4];
  const float* bhh  = (const float*)d_in[5];
  const float* W1   = (const float*)d_in[6];
  const float* b1   = (const float*)d_in[7];
  const float* W2   = (const float*)d_in[8];
  const float* b2   = (const float*)d_in[9];
  float* out = (float*)d_out;

  const size_t splitBytes = (size_t)kW1Elems * sizeof(short) * 2;
  dim3 grid(8192/16), block(256);
  if (ws_size >= splitBytes) {
    short* W1h = (short*)d_ws;
    short* W1l = W1h + kW1Elems;
    hipLaunchKernelGGL(presplit_w1, dim3((kW1Elems+255)/256), dim3(256), 0, stream,
                       W1, W1h, W1l);
    hipLaunchKernelGGL(lstm_pipe<true>, grid, block, 0, stream,
                       x, Wih0, Wihr, Whh, bih, bhh, W1, b1, W2, b2, W1h, W1l, out);
  } else {
    hipLaunchKernelGGL(lstm_pipe<false>, grid, block, 0, stream,
                       x, Wih0, Wihr, Whh, bih, bhh, W1, b1, W2, b2,
                       (const short*)nullptr, (const short*)nullptr, out);
  }
}

// Round 7
// 265.489 us; speedup vs baseline: 3.6112x; 1.1050x over previous
//
#include <hip/hip_runtime.h>
#include <hip/hip_bf16.h>

// ---------------------------------------------------------------------------
// Pipelined MFMA LSTM (B=8192,T=200,IN=4,H=16) + fused MLP (3200->64->28).
//   - block = 4 waves = one 16-sample group; wave l owns layer l AND MLP tile l
//   - software pipeline over timestep QUADS: superstep n, wave l computes
//     t = 4(n-l)..4(n-l)+3; ONE barrier per 4 timesteps (54 total)
//   - h stored in LDS as PRE-SPLIT bf16 hi/lo planes (trunc, bit-identical to
//     consumer split8): consumers ds_read_b128 MFMA-ready frags, zero VALU
//   - rows padded to 24 ushorts (48B: 16-aligned b128, banks spread)
//   - steps 1..3 read own-state from just-written same-parity slots
//     (same-wave lgkmcnt ordering); step 0 from prev-parity slot 3
//   - per layer: G[64,32] = [Wih|Whh] @ [h_{l-1};h_l] via mfma_f32_16x16x32_bf16
//     (3-term trunc hi/lo bf16 split for fp32-grade accuracy)
//   - MLP tile l: 2 pairs (K=32 each, 6 MFMA) per superstep; W1 pre-split in
//     d_ws, prefetched 1 superstep ahead into SEPARATE N/C reg sets (R5 lesson)
// ---------------------------------------------------------------------------

typedef short  bf16x8 __attribute__((ext_vector_type(8)));
typedef float  f32x4  __attribute__((ext_vector_type(4)));
typedef unsigned int uint2v __attribute__((ext_vector_type(2)));

namespace {
constexpr int kT    = 200;
constexpr int kOut  = 28;
constexpr int kQ    = kT / 4;          // 50 quads
constexpr int kSteps = kQ + 4;         // 54
constexpr float kNLog2e  = -1.4426950408889634f;   // -log2(e)
constexpr float kN2Log2e = -2.8853900817779268f;   // -2*log2(e)
constexpr int kW1Elems = 64 * 3200;
}

union FragU { bf16x8 v; unsigned u[4]; };

__device__ __forceinline__ float fast_rcp(float v){ return __builtin_amdgcn_rcpf(v); }
__device__ __forceinline__ float fast_exp2(float v){ return __builtin_amdgcn_exp2f(v); }
// input already scaled by -log2e (folded into weights+bias)
__device__ __forceinline__ float sig_scaled(float p){ return fast_rcp(1.0f + fast_exp2(p)); }
__device__ __forceinline__ float tanh_true(float v){
  return fmaf(fast_rcp(1.0f + fast_exp2(kN2Log2e*v)), 2.0f, -1.0f);
}

// trunc-split 8 f32 -> bf16 hi frag + bf16 lo frag
__device__ __forceinline__ void split8(const float* v, FragU& hi, FragU& lo){
#pragma unroll
  for (int r=0;r<4;++r){
    unsigned ua=__float_as_uint(v[2*r]), ub=__float_as_uint(v[2*r+1]);
    hi.u[r] = (ua>>16) | (ub & 0xffff0000u);
    float af=__uint_as_float(ua & 0xffff0000u);
    float bf=__uint_as_float(ub & 0xffff0000u);
    float al=v[2*r]-af, bl=v[2*r+1]-bf;
    lo.u[r] = (__float_as_uint(al)>>16) | (__float_as_uint(bl) & 0xffff0000u);
  }
}

__global__ __launch_bounds__(256)
void presplit_w1(const float* __restrict__ W1,
                 short* __restrict__ W1h, short* __restrict__ W1l){
  int i = blockIdx.x*256 + threadIdx.x;
  if (i < kW1Elems){
    float v = W1[i];
    unsigned u = __float_as_uint(v);
    float hif = __uint_as_float(u & 0xffff0000u);
    float lo  = v - hif;
    W1h[i] = (short)(u >> 16);
    W1l[i] = (short)(__float_as_uint(lo) >> 16);
  }
}

// index into packed-h planes: [parity][layer][slot][sample][j pad 24]
#define HIDX(pp,ll,ss,sa,jj) (((((pp)*4+(ll))*4+(ss))*16+(sa))*24+(jj))

template<bool PS>
__global__ __launch_bounds__(256)
void lstm_pipe(const float* __restrict__ x,     // [B,T,4]
               const float* __restrict__ Wih0,  // [64,4]
               const float* __restrict__ Wihr,  // [3,64,16]
               const float* __restrict__ Whh,   // [4,64,16]
               const float* __restrict__ bih,   // [4,64]
               const float* __restrict__ bhh,   // [4,64]
               const float* __restrict__ W1,    // [64,3200]
               const float* __restrict__ b1,    // [64]
               const float* __restrict__ W2,    // [28,64]
               const float* __restrict__ b2,    // [28]
               const short* __restrict__ W1h,   // [64,3200] bf16 hi plane
               const short* __restrict__ W1l,   // [64,3200] bf16 lo plane
               float* __restrict__ out)         // [B,28]
{
  __shared__ unsigned short Hh[2][4][4][16][24];  // packed h, hi plane
  __shared__ unsigned short Hl[2][4][4][16][24];  // packed h, lo plane
  __shared__ float ldsR[16][68];                  // relu(hid), padded

  const int tid  = threadIdx.x;
  const int lane = tid & 63;
  const int wv   = tid >> 6;            // 0..3: layer index AND mlp tile index
  const int s    = lane & 15;           // sample within group (= MFMA col)
  const int q    = lane >> 4;           // lane quadrant (= k-chunk / row group)
  const int l    = wv;
  const int lm1  = (l==0) ? 0 : (l-1);
  const int sbase = blockIdx.x * 16;

  for (int i = tid; i < 2*4*4*16*24/2; i += 256){
    ((unsigned*)Hh)[i] = 0u;
    ((unsigned*)Hl)[i] = 0u;
  }

  // ---- A fragments for THIS wave's layer: row=lane&15, k=q*8+e, tile=gate
  FragU A[4][2];
#pragma unroll
  for (int tile=0;tile<4;++tile){
    const int grow = tile*16 + s;
    const float kE = (tile==2)? kN2Log2e : kNLog2e;
    float v[8];
    if (l==0){
#pragma unroll
      for (int e=0;e<8;++e){
        float w = 0.f;
        if (q==0 && e<4) w = Wih0[grow*4+e];
        if (q>=2)        w = Whh[grow*16 + (q&1)*8 + e];
        v[e] = w*kE;
      }
    } else {
#pragma unroll
      for (int e=0;e<8;++e){
        float w = (q<2) ? Wihr[((l-1)*64+grow)*16 + q*8 + e]
                        : Whh [(( l )*64+grow)*16 + (q&1)*8 + e];
        v[e] = w*kE;
      }
    }
    split8(v, A[tile][0], A[tile][1]);
  }

  // ---- scaled bias in VGPRs (C-init)
  f32x4 biasf[4];
#pragma unroll
  for (int tile=0;tile<4;++tile){
    const float kE = (tile==2)? kN2Log2e : kNLog2e;
#pragma unroll
    for (int r=0;r<4;++r){
      const int row = l*64 + tile*16 + 4*q + r;
      biasf[tile][r] = (bih[row] + bhh[row]) * kE;
    }
  }

  float cst[4] = {0.f,0.f,0.f,0.f};
  f32x4 mlpacc = (f32x4){0.f,0.f,0.f,0.f};

  const float* xp = x + (size_t)(sbase+s)*(kT*4);
  float4 xc0,xc1,xc2,xc3;               // current quad's x (wave 0)
  if (l==0){
    xc0 = *(const float4*)(xp+ 0); xc1 = *(const float4*)(xp+ 4);
    xc2 = *(const float4*)(xp+ 8); xc3 = *(const float4*)(xp+12);
  }

  const int rowW1 = wv*16 + s;
  const short* w1hp = W1h + (size_t)rowW1*3200;
  const short* w1lp = W1l + (size_t)rowW1*3200;
  const float* w1fp = W1  + (size_t)rowW1*3200;
  // prefetch double-buffer: N = loaded this superstep, C = consumed this one
  FragU  pWhC0,pWlC0,pWhC1,pWlC1, pWhN0,pWlN0,pWhN1,pWlN1;
  float4 pWaC0,pWbC0,pWaC1,pWbC1, pWaN0,pWbN0,pWaN1,pWbN1;

  __syncthreads();

#pragma unroll 2
  for (int n=0; n<kSteps; ++n){
    const int p = n & 1;

    // ---- 1) W1 prefetch for MLP quad (n-3): pairs 2(n-3), 2(n-3)+1
    {
      const int mp = n - 3;
      if (mp >= 0 && mp < kQ){
        const int off = 64*mp + q*8;
        if (PS){
          pWhN0.v = *(const bf16x8*)(w1hp + off);
          pWlN0.v = *(const bf16x8*)(w1lp + off);
          pWhN1.v = *(const bf16x8*)(w1hp + off + 32);
          pWlN1.v = *(const bf16x8*)(w1lp + off + 32);
        } else {
          pWaN0 = *(const float4*)(w1fp + off);
          pWbN0 = *(const float4*)(w1fp + off + 4);
          pWaN1 = *(const float4*)(w1fp + off + 32);
          pWbN1 = *(const float4*)(w1fp + off + 36);
        }
      }
    }
    const int pr = n - l;                 // this wave's quad
    // ---- 1b) x prefetch for next quad (wave 0)
    float4 xn0,xn1,xn2,xn3;
    if (l==0 && pr+1 < kQ){
      const float* xq = xp + 16*(pr+1);
      xn0 = *(const float4*)(xq+ 0); xn1 = *(const float4*)(xq+ 4);
      xn2 = *(const float4*)(xq+ 8); xn3 = *(const float4*)(xq+12);
    }

    // ---- 2) recurrent layer l, four timesteps of quad pr
    if (pr >= 0 && pr < kQ){
#pragma unroll
      for (int st=0; st<4; ++st){
        // B operand source (packed bf16 hi/lo planes):
        //  q0,q1 <- h_{l-1}(4pr+st) = prev-parity slot st of layer l-1
        //  q2,q3 <- h_l(4pr+st-1)   = st==0 ? prev-parity slot 3 : own slot st-1
        int rp, rl, rs;
        if (q < 2){ rp = p^1; rl = lm1; rs = st; }
        else if (st == 0){ rp = p^1; rl = l; rs = 3; }
        else { rp = p; rl = l; rs = st-1; }
        const int ridx = HIDX(rp, rl, rs, s, (q&1)*8);
        FragU Bh, Bl;
        Bh.v = *(const bf16x8*)&((const unsigned short*)Hh)[ridx];
        Bl.v = *(const bf16x8*)&((const unsigned short*)Hl)[ridx];
        if (l==0){
          const float4 xv = (st==0)?xc0:(st==1)?xc1:(st==2)?xc2:xc3;
          if (q==0){
            const unsigned u0=__float_as_uint(xv.x), u1=__float_as_uint(xv.y);
            const unsigned u2=__float_as_uint(xv.z), u3=__float_as_uint(xv.w);
            Bh.u[0] = (u0>>16)|(u1&0xffff0000u);
            Bh.u[1] = (u2>>16)|(u3&0xffff0000u);
            Bh.u[2] = 0u; Bh.u[3] = 0u;
            const float f0 = xv.x-__uint_as_float(u0&0xffff0000u);
            const float f1 = xv.y-__uint_as_float(u1&0xffff0000u);
            const float f2 = xv.z-__uint_as_float(u2&0xffff0000u);
            const float f3 = xv.w-__uint_as_float(u3&0xffff0000u);
            Bl.u[0] = (__float_as_uint(f0)>>16)|(__float_as_uint(f1)&0xffff0000u);
            Bl.u[1] = (__float_as_uint(f2)>>16)|(__float_as_uint(f3)&0xffff0000u);
            Bl.u[2] = 0u; Bl.u[3] = 0u;
          } else if (q==1){
#pragma unroll
            for (int r=0;r<4;++r){ Bh.u[r]=0u; Bl.u[r]=0u; }
          }
        }

        float si[4], sf[4], sg[4], so[4];
#pragma unroll
        for (int tile=0;tile<4;++tile){
          f32x4 acc = biasf[tile];
          acc = __builtin_amdgcn_mfma_f32_16x16x32_bf16(A[tile][0].v,Bh.v,acc,0,0,0);
          acc = __builtin_amdgcn_mfma_f32_16x16x32_bf16(A[tile][0].v,Bl.v,acc,0,0,0);
          acc = __builtin_amdgcn_mfma_f32_16x16x32_bf16(A[tile][1].v,Bh.v,acc,0,0,0);
#pragma unroll
          for (int r=0;r<4;++r){
            const float a = sig_scaled(acc[r]);
            if      (tile==0) si[r]=a;
            else if (tile==1) sf[r]=a;
            else if (tile==2) sg[r]=fmaf(a,2.f,-1.f);
            else              so[r]=a;
          }
        }
        float hn[4];
#pragma unroll
        for (int r=0;r<4;++r){
          cst[r] = fmaf(sf[r], cst[r], si[r]*sg[r]);
          hn[r] = so[r]*tanh_true(cst[r]);
        }
        // producer-side trunc pack -> bf16 hi/lo planes (bit-identical split)
        {
          const unsigned u0=__float_as_uint(hn[0]), u1=__float_as_uint(hn[1]);
          const unsigned u2=__float_as_uint(hn[2]), u3=__float_as_uint(hn[3]);
          const unsigned hi01 = (u0>>16)|(u1&0xffff0000u);
          const unsigned hi23 = (u2>>16)|(u3&0xffff0000u);
          const float f0 = hn[0]-__uint_as_float(u0&0xffff0000u);
          const float f1 = hn[1]-__uint_as_float(u1&0xffff0000u);
          const float f2 = hn[2]-__uint_as_float(u2&0xffff0000u);
          const float f3 = hn[3]-__uint_as_float(u3&0xffff0000u);
          const unsigned lo01 = (__float_as_uint(f0)>>16)|(__float_as_uint(f1)&0xffff0000u);
          const unsigned lo23 = (__float_as_uint(f2)>>16)|(__float_as_uint(f3)&0xffff0000u);
          const int widx = HIDX(p, l, st, s, 4*q);
          *(uint2v*)&((unsigned short*)Hh)[widx] = (uint2v){hi01,hi23};
          *(uint2v*)&((unsigned short*)Hl)[widx] = (uint2v){lo01,lo23};
        }
      }
    }
    if (l==0 && pr+1 < kQ){ xc0=xn0; xc1=xn1; xc2=xn2; xc3=xn3; }

    // ---- 3) MLP tile wv for quad m = n-4: pairs 2m, 2m+1 (K=32 each)
    {
      const int m = n - 4;
      if (m >= 0 && m < kQ){
#pragma unroll
        for (int pp=0; pp<2; ++pp){
          const int bidx = HIDX(p^1, 3, 2*pp + (q>>1), s, (q&1)*8);
          FragU Bh, Bl;
          Bh.v = *(const bf16x8*)&((const unsigned short*)Hh)[bidx];
          Bl.v = *(const bf16x8*)&((const unsigned short*)Hl)[bidx];
          FragU Ah, Al;
          if (PS){
            Ah = pp ? pWhC1 : pWhC0;
            Al = pp ? pWlC1 : pWlC0;
          } else {
            const float4 wa = pp ? pWaC1 : pWaC0;
            const float4 wb = pp ? pWbC1 : pWbC0;
            float v[8] = {wa.x,wa.y,wa.z,wa.w,wb.x,wb.y,wb.z,wb.w};
            split8(v,Ah,Al);
          }
          mlpacc = __builtin_amdgcn_mfma_f32_16x16x32_bf16(Ah.v,Bh.v,mlpacc,0,0,0);
          mlpacc = __builtin_amdgcn_mfma_f32_16x16x32_bf16(Ah.v,Bl.v,mlpacc,0,0,0);
          mlpacc = __builtin_amdgcn_mfma_f32_16x16x32_bf16(Al.v,Bh.v,mlpacc,0,0,0);
        }
      }
    }
    // rotate prefetch regs AFTER consume (compiler renames on unroll)
    if (PS){ pWhC0=pWhN0; pWlC0=pWlN0; pWhC1=pWhN1; pWlC1=pWlN1; }
    else   { pWaC0=pWaN0; pWbC0=pWbN0; pWaC1=pWaN1; pWbC1=pWbN1; }
    __syncthreads();
  }

  // ---- epilogue: relu -> ldsR; W2 stage spread over the 4 waves
  {
    f32x4 rv;
#pragma unroll
    for (int r=0;r<4;++r)
      rv[r] = fmaxf(mlpacc[r] + b1[wv*16 + 4*q + r], 0.f);
    *(f32x4*)&ldsR[s][wv*16 + 4*q] = rv;
  }
  __syncthreads();
  {
    const int o  = lane & 31;
    const int oc = (o < kOut) ? o : 0;
    float4 w2r[16];
#pragma unroll
    for (int c2=0;c2<16;++c2) w2r[c2] = *(const float4*)(W2 + oc*64 + 4*c2);
    const float bias2 = b2[oc];
#pragma unroll
    for (int mm=0;mm<2;++mm){
      const int s2 = wv*4 + 2*mm + (lane>>5);
      float a0=bias2, a1=0.f, a2=0.f, a3=0.f;
#pragma unroll
      for (int c2=0;c2<16;++c2){
        const float4 rvv = *(const float4*)&ldsR[s2][4*c2];
        a0 = fmaf(w2r[c2].x, rvv.x, a0);
        a1 = fmaf(w2r[c2].y, rvv.y, a1);
        a2 = fmaf(w2r[c2].z, rvv.z, a2);
        a3 = fmaf(w2r[c2].w, rvv.w, a3);
      }
      if (o < kOut) out[(size_t)(sbase+s2)*kOut + o] = (a0+a1)+(a2+a3);
    }
  }
}

extern "C" void kernel_launch(void* const* d_in, const int* in_sizes, int n_in,
                              void* d_out, int out_size, void* d_ws, size_t ws_size,
                              hipStream_t stream) {
  (void)in_sizes; (void)n_in; (void)out_size;
  const float* x    = (const float*)d_in[0];
  const float* Wih0 = (const float*)d_in[1];
  const float* Wihr = (const float*)d_in[2];
  const float* Whh  = (const float*)d_in[3];
  const float* bih  = (const float*)d_in[4];
  const float* bhh  = (const float*)d_in[5];
  const float* W1   = (const float*)d_in[6];
  const float* b1   = (const float*)d_in[7];
  const float* W2   = (const float*)d_in[8];
  const float* b2   = (const float*)d_in[9];
  float* out = (float*)d_out;

  const size_t splitBytes = (size_t)kW1Elems * sizeof(short) * 2;
  dim3 grid(8192/16), block(256);
  if (ws_size >= splitBytes) {
    short* W1h = (short*)d_ws;
    short* W1l = W1h + kW1Elems;
    hipLaunchKernelGGL(presplit_w1, dim3((kW1Elems+255)/256), dim3(256), 0, stream,
                       W1, W1h, W1l);
    hipLaunchKernelGGL(lstm_pipe<true>, grid, block, 0, stream,
                       x, Wih0, Wihr, Whh, bih, bhh, W1, b1, W2, b2, W1h, W1l, out);
  } else {
    hipLaunchKernelGGL(lstm_pipe<false>, grid, block, 0, stream,
                       x, Wih0, Wihr, Whh, bih, bhh, W1, b1, W2, b2,
                       (const short*)nullptr, (const short*)nullptr, out);
  }
}